// Round 1
// baseline (21328.357 us; speedup 1.0000x reference)
//
#include <hip/hip_runtime.h>

#define NOP   2048
#define NROWS 8192
#define NACT  1024
#define NB    32
#define NBLK  256
#define NTHR  256

typedef _Float16 f16;
typedef _Float16 h2t __attribute__((ext_vector_type(2)));

// ---------- helpers ----------

template <int CTRL>
__device__ __forceinline__ float dpp_add(float x) {
  union { float f; int i; } a, r;
  a.f = x;
  r.i = __builtin_amdgcn_update_dpp(0, a.i, CTRL, 0xF, 0xF, true);
  return x + r.f;
}

// full 64-lane sum; total lands in lane 63 (VALU-only, keeps DS pipe free)
__device__ __forceinline__ float wave_sum63(float x) {
  x = dpp_add<0x111>(x);  // row_shr:1
  x = dpp_add<0x112>(x);  // row_shr:2
  x = dpp_add<0x114>(x);  // row_shr:4
  x = dpp_add<0x118>(x);  // row_shr:8  -> lane15/31/47/63 hold row sums
  x = dpp_add<0x142>(x);  // row_bcast15
  x = dpp_add<0x143>(x);  // row_bcast31 -> lane63 = total
  return x;
}

__device__ __forceinline__ float dot8(float4 wv, float4 hv, float acc) {
  union U { float f; h2t v; };
  U w0{wv.x}, w1{wv.y}, w2{wv.z}, w3{wv.w};
  U h0{hv.x}, h1{hv.y}, h2{hv.z}, h3{hv.w};
#if __has_builtin(__builtin_amdgcn_fdot2)
  acc = __builtin_amdgcn_fdot2(w0.v, h0.v, acc, false);
  acc = __builtin_amdgcn_fdot2(w1.v, h1.v, acc, false);
  acc = __builtin_amdgcn_fdot2(w2.v, h2.v, acc, false);
  acc = __builtin_amdgcn_fdot2(w3.v, h3.v, acc, false);
#else
  acc += (float)w0.v.x * (float)h0.v.x + (float)w0.v.y * (float)h0.v.y;
  acc += (float)w1.v.x * (float)h1.v.x + (float)w1.v.y * (float)h1.v.y;
  acc += (float)w2.v.x * (float)h2.v.x + (float)w2.v.y * (float)h2.v.y;
  acc += (float)w3.v.x * (float)h3.v.x + (float)w3.v.y * (float)h3.v.y;
#endif
  return acc;
}

__device__ __forceinline__ float sigmoid_f(float x) {
  return 1.0f / (1.0f + __expf(-x));
}
// overflow-safe tanh
__device__ __forceinline__ float tanh_f(float x) {
  float ax = fabsf(x);
  float e = __expf(-2.0f * ax);
  float r = (1.0f - e) / (1.0f + e);
  return copysignf(r, x);
}

// ---------- prep kernels ----------

// x_gates[r] = (1/NOP) * sum_k W_ih[r][k] + b_ih[r] + b_hh[r]
extern "C" __global__ __launch_bounds__(256) void prep_xg(
    const float* __restrict__ Wih, const float* __restrict__ bih,
    const float* __restrict__ bhh, float* __restrict__ xg) {
  int row = blockIdx.x * 4 + (threadIdx.x >> 6);
  int ln = threadIdx.x & 63;
  const float4* src = (const float4*)(Wih + (size_t)row * NOP);
  float s = 0.f;
#pragma unroll
  for (int c = 0; c < 8; ++c) {
    float4 v = src[c * 64 + ln];
    s += v.x + v.y + v.z + v.w;
  }
#pragma unroll
  for (int off = 32; off >= 1; off >>= 1) s += __shfl_xor(s, off);
  if (ln == 0) xg[row] = s * (1.0f / NOP) + bih[row] + bhh[row];
}

// pack W_hh (f32) -> fp16, layout [block b][local row r][c][lane][8 halves]
// local row r = gate*8 + jj ; global row = gate*NOP + b*8 + jj ; k = lane*32 + c*8
extern "C" __global__ __launch_bounds__(256) void prep_pack(
    const float* __restrict__ Whh, f16* __restrict__ Wp) {
  int tid = blockIdx.x * 256 + threadIdx.x;  // one 16B chunk each, 2M total
  int l = tid & 63;
  int c = (tid >> 6) & 3;
  int r = (tid >> 8) & 31;
  int b = tid >> 13;
  int gate = r >> 3, jj = r & 7;
  int grow = gate * NOP + b * 8 + jj;
  int k = l * 32 + c * 8;
  const float4* src = (const float4*)(Whh + (size_t)grow * NOP + k);
  float4 a = src[0], b2 = src[1];
  union { f16 h[8]; float4 v; } o;
  o.h[0] = (f16)a.x;  o.h[1] = (f16)a.y;  o.h[2] = (f16)a.z;  o.h[3] = (f16)a.w;
  o.h[4] = (f16)b2.x; o.h[5] = (f16)b2.y; o.h[6] = (f16)b2.z; o.h[7] = (f16)b2.w;
  ((float4*)Wp)[tid] = o.v;
}

// ---------- persistent LSTM kernel ----------
// 256 blocks x 256 threads, cooperative. Block b owns h/c elements [b*8, b*8+8)
// and gate rows {j, j+2048, j+4096, j+6144}. Weights live in LDS (128 KiB).
extern "C" __global__ void __launch_bounds__(NTHR) lstm_main(
    const float* __restrict__ xg_g, const f16* __restrict__ Wp,
    float* __restrict__ outputs, unsigned* __restrict__ flags) {
  extern __shared__ char smem[];
  f16*   w_lds = (f16*)smem;                        // 65536 halves = 128 KiB
  f16*   h4    = (f16*)(smem + 131072);             // [c:4][lane:64][8] = 4 KiB
  float* g_buf = (float*)(smem + 131072 + 4096);    // 32 f32
  float* xg_s  = g_buf + 32;                        // 32 f32

  const int b   = blockIdx.x;
  const int tid = threadIdx.x;
  const int w   = tid >> 6;
  const int ln  = tid & 63;

  {  // stage this block's weights into LDS once
    const float4* src = (const float4*)(Wp + (size_t)b * 65536);
    float4* dst = (float4*)w_lds;
    for (int i = tid; i < 8192; i += NTHR) dst[i] = src[i];
  }
  if (tid < 32) {
    int gate = tid >> 3, jj = tid & 7;
    xg_s[tid] = xg_g[gate * NOP + b * 8 + jj];
  }
  float c_state = 0.f;  // live in tid<8 only
  __syncthreads();

  for (int t = 0; t < NACT; ++t) {
    if (t > 0) {
      // ---- device-wide barrier: wait until every block published h(t-1) ----
      if (w == 0) {
        const unsigned tu = (unsigned)t;
        const int base = ln * 4;
        for (;;) {
          unsigned f0 = __hip_atomic_load(&flags[base + 0], __ATOMIC_ACQUIRE, __HIP_MEMORY_SCOPE_AGENT);
          unsigned f1 = __hip_atomic_load(&flags[base + 1], __ATOMIC_ACQUIRE, __HIP_MEMORY_SCOPE_AGENT);
          unsigned f2 = __hip_atomic_load(&flags[base + 2], __ATOMIC_ACQUIRE, __HIP_MEMORY_SCOPE_AGENT);
          unsigned f3 = __hip_atomic_load(&flags[base + 3], __ATOMIC_ACQUIRE, __HIP_MEMORY_SCOPE_AGENT);
          bool ok = (f0 >= tu) & (f1 >= tu) & (f2 >= tu) & (f3 >= tu);
          if (__all(ok)) break;
        }
      }
      __syncthreads();

      // ---- load h(t-1), convert to fp16, stash in LDS ----
      const float* hp = outputs + (size_t)(t - 1) * NOP;
      float4 ha = *((const float4*)(hp + tid * 8));
      float4 hb = *((const float4*)(hp + tid * 8 + 4));
      union { f16 a[8]; float4 v; } pk;
      pk.a[0] = (f16)ha.x; pk.a[1] = (f16)ha.y; pk.a[2] = (f16)ha.z; pk.a[3] = (f16)ha.w;
      pk.a[4] = (f16)hb.x; pk.a[5] = (f16)hb.y; pk.a[6] = (f16)hb.z; pk.a[7] = (f16)hb.w;
      const int cc = tid & 3, l2i = tid >> 2;
      *((float4*)(h4 + ((cc * 64 + l2i) * 8))) = pk.v;
      __syncthreads();

      // ---- matvec: wave w owns local rows w*8..w*8+7; lane ln owns k-slice ----
      float4 hreg[4];
#pragma unroll
      for (int c = 0; c < 4; ++c)
        hreg[c] = *((const float4*)(h4 + ((c * 64 + ln) * 8)));

#pragma unroll
      for (int r = 0; r < 8; ++r) {
        float acc = 0.f;
#pragma unroll
        for (int c = 0; c < 4; ++c) {
          float4 wv = *((const float4*)(w_lds + (((((w * 8 + r) * 4) + c) * 64 + ln) * 8)));
          acc = dot8(wv, hreg[c], acc);
        }
        acc = wave_sum63(acc);
        if (ln == 63) g_buf[w * 8 + r] = acc + xg_s[w * 8 + r];
      }
    } else {
      if (tid < 32) g_buf[tid] = xg_s[tid];  // h(0)=0 -> g = x_gates
    }
    __syncthreads();

    // ---- gate activations + state update (block-local) ----
    if (tid < 8) {
      float gi = g_buf[tid],      gf = g_buf[8 + tid];
      float gc = g_buf[16 + tid], go = g_buf[24 + tid];
      float i_ = sigmoid_f(gi);
      float f_ = sigmoid_f(gf);
      float g_ = tanh_f(gc);
      float o_ = sigmoid_f(go);
      c_state = f_ * c_state + i_ * g_;
      float h = o_ * tanh_f(c_state);
      __hip_atomic_store(&outputs[(size_t)t * NOP + b * 8 + tid], h,
                         __ATOMIC_RELAXED, __HIP_MEMORY_SCOPE_AGENT);
    }
    __syncthreads();  // drains vmem before flag publish
    if (tid == 0)
      __hip_atomic_store(&flags[b], (unsigned)(t + 1),
                         __ATOMIC_RELEASE, __HIP_MEMORY_SCOPE_AGENT);
  }
}

// ---------- phase 2: entropy + reinforce ----------
extern "C" __global__ __launch_bounds__(256) void phase2(
    const float* __restrict__ outputs, const float* __restrict__ rewards,
    const int* __restrict__ action, float* __restrict__ accum) {
  __shared__ float sm[4], s1s[4], s2s[4];
  __shared__ float bc[2];
  const int t = blockIdx.x, tid = threadIdx.x, w = tid >> 6, ln = tid & 63;
  const float* row = outputs + (size_t)t * NOP;
  const float4* r4 = (const float4*)row;
  float4 a = r4[tid], b4 = r4[tid + 256];

  float m = fmaxf(fmaxf(fmaxf(a.x, a.y), fmaxf(a.z, a.w)),
                  fmaxf(fmaxf(b4.x, b4.y), fmaxf(b4.z, b4.w)));
#pragma unroll
  for (int off = 32; off >= 1; off >>= 1) m = fmaxf(m, __shfl_xor(m, off));
  if (ln == 0) sm[w] = m;
  __syncthreads();
  if (tid == 0) bc[0] = fmaxf(fmaxf(sm[0], sm[1]), fmaxf(sm[2], sm[3]));
  __syncthreads();
  const float M = bc[0];

  float s1 = 0.f, s2 = 0.f;
  {
    float xs[8] = {a.x, a.y, a.z, a.w, b4.x, b4.y, b4.z, b4.w};
#pragma unroll
    for (int u = 0; u < 8; ++u) {
      float d = xs[u] - M;
      float p = __expf(d);
      s1 += p;
      s2 += d * p;
    }
  }
#pragma unroll
  for (int off = 32; off >= 1; off >>= 1) {
    s1 += __shfl_xor(s1, off);
    s2 += __shfl_xor(s2, off);
  }
  if (ln == 0) { s1s[w] = s1; s2s[w] = s2; }
  __syncthreads();
  if (tid == 0) {
    float S1 = s1s[0] + s1s[1] + s1s[2] + s1s[3];
    float S2 = s2s[0] + s2s[1] + s2s[2] + s2s[3];
    float lse = M + logf(S1);
    atomicAdd(&accum[1], logf(S1) - S2 / S1);  // entropy of this row
    bc[1] = lse;
  }
  __syncthreads();
  if (tid < 32) {  // tid == batch index b
    int ai = action[tid * NACT + t] & (NOP - 1);
    float val = row[ai] - bc[1];
    float rr = rewards[tid] * val;
#pragma unroll
    for (int off = 16; off >= 1; off >>= 1) rr += __shfl_xor(rr, off);
    if (tid == 0) atomicAdd(&accum[0], rr);  // sum of rewards*gathered
  }
}

extern "C" __global__ void finalize(const float* __restrict__ accum,
                                    float* __restrict__ out) {
  // loss = (-sum(rewards*gathered) + NB*entropy_sum)/NB
  out[0] = accum[1] - accum[0] * (1.0f / NB);
}

// ---------- launch ----------
extern "C" void kernel_launch(void* const* d_in, const int* in_sizes, int n_in,
                              void* d_out, int out_size, void* d_ws, size_t ws_size,
                              hipStream_t stream) {
  const float* W_ih   = (const float*)d_in[0];
  const float* W_hh   = (const float*)d_in[1];
  const float* b_ih   = (const float*)d_in[2];
  const float* b_hh   = (const float*)d_in[3];
  const float* rewards = (const float*)d_in[4];
  const int*   action  = (const int*)d_in[5];

  char* ws = (char*)d_ws;
  unsigned* flags  = (unsigned*)ws;                   // 1 KiB
  float*    accum  = (float*)(ws + 1024);             // 8 B
  float*    xg     = (float*)(ws + 4096);             // 32 KiB
  float*    outputs = (float*)(ws + 65536);           // 8 MiB
  f16*      Wp     = (f16*)(ws + 16u * 1024 * 1024);  // 32 MiB

  hipMemsetAsync(ws, 0, 4096, stream);  // flags + accumulators

  hipLaunchKernelGGL(prep_xg, dim3(NROWS / 4), dim3(256), 0, stream,
                     W_ih, b_ih, b_hh, xg);
  hipLaunchKernelGGL(prep_pack, dim3(NROWS), dim3(256), 0, stream, W_hh, Wp);

  const unsigned smem = 131072 + 4096 + 256;  // weights + h4 + g_buf/xg_s
  hipFuncSetAttribute((const void*)lstm_main,
                      hipFuncAttributeMaxDynamicSharedMemorySize, (int)smem);
  void* args[] = {(void*)&xg, (void*)&Wp, (void*)&outputs, (void*)&flags};
  hipLaunchCooperativeKernel((void*)lstm_main, dim3(NBLK), dim3(NTHR), args,
                             smem, stream);

  hipLaunchKernelGGL(phase2, dim3(NACT), dim3(256), 0, stream,
                     outputs, rewards, action, accum);
  hipLaunchKernelGGL(finalize, dim3(1), dim3(1), 0, stream, accum, (float*)d_out);
}

// Round 2
// 5236.725 us; speedup vs baseline: 4.0728x; 4.0728x over previous
//
#include <hip/hip_runtime.h>

#define NOP   2048
#define NROWS 8192
#define NACT  1024
#define NB    32
#define NBLK  256
#define NTHR  256

typedef _Float16 f16;
typedef _Float16 h2t __attribute__((ext_vector_type(2)));
typedef unsigned long long u64t;
typedef unsigned int u32t;

// ---------- helpers ----------

template <int CTRL>
__device__ __forceinline__ float dpp_add(float x) {
  union { float f; int i; } a, r;
  a.f = x;
  r.i = __builtin_amdgcn_update_dpp(0, a.i, CTRL, 0xF, 0xF, true);
  return x + r.f;
}

// full 64-lane sum; total lands in lane 63 (VALU-only, keeps DS pipe free)
__device__ __forceinline__ float wave_sum63(float x) {
  x = dpp_add<0x111>(x);  // row_shr:1
  x = dpp_add<0x112>(x);  // row_shr:2
  x = dpp_add<0x114>(x);  // row_shr:4
  x = dpp_add<0x118>(x);  // row_shr:8  -> lane15/31/47/63 hold row sums
  x = dpp_add<0x142>(x);  // row_bcast15
  x = dpp_add<0x143>(x);  // row_bcast31 -> lane63 = total
  return x;
}

__device__ __forceinline__ float dot8(float4 wv, float4 hv, float acc) {
  union U { float f; h2t v; };
  U w0{wv.x}, w1{wv.y}, w2{wv.z}, w3{wv.w};
  U h0{hv.x}, h1{hv.y}, h2{hv.z}, h3{hv.w};
#if __has_builtin(__builtin_amdgcn_fdot2)
  acc = __builtin_amdgcn_fdot2(w0.v, h0.v, acc, false);
  acc = __builtin_amdgcn_fdot2(w1.v, h1.v, acc, false);
  acc = __builtin_amdgcn_fdot2(w2.v, h2.v, acc, false);
  acc = __builtin_amdgcn_fdot2(w3.v, h3.v, acc, false);
#else
  acc += (float)w0.v.x * (float)h0.v.x + (float)w0.v.y * (float)h0.v.y;
  acc += (float)w1.v.x * (float)h1.v.x + (float)w1.v.y * (float)h1.v.y;
  acc += (float)w2.v.x * (float)h2.v.x + (float)w2.v.y * (float)h2.v.y;
  acc += (float)w3.v.x * (float)h3.v.x + (float)w3.v.y * (float)h3.v.y;
#endif
  return acc;
}

__device__ __forceinline__ float sigmoid_f(float x) {
  return 1.0f / (1.0f + __expf(-x));
}
// overflow-safe tanh
__device__ __forceinline__ float tanh_f(float x) {
  float ax = fabsf(x);
  float e = __expf(-2.0f * ax);
  float r = (1.0f - e) / (1.0f + e);
  return copysignf(r, x);
}

// ---------- prep: pack W_hh (f32) -> fp16 ----------
// layout [block b][local row r:32][c:4][lane:64][8 halves]
// local row r = gate*8 + jj ; global row = gate*NOP + b*8 + jj ; k = lane*32 + c*8
extern "C" __global__ __launch_bounds__(256) void prep_pack(
    const float* __restrict__ Whh, f16* __restrict__ Wp) {
  int tid = blockIdx.x * 256 + threadIdx.x;  // one 16B chunk each, 2M total
  int l = tid & 63;
  int c = (tid >> 6) & 3;
  int r = (tid >> 8) & 31;
  int b = tid >> 13;
  int gate = r >> 3, jj = r & 7;
  int grow = gate * NOP + b * 8 + jj;
  int k = l * 32 + c * 8;
  const float4* src = (const float4*)(Whh + (size_t)grow * NOP + k);
  float4 a = src[0], b2 = src[1];
  union { f16 h[8]; float4 v; } o;
  o.h[0] = (f16)a.x;  o.h[1] = (f16)a.y;  o.h[2] = (f16)a.z;  o.h[3] = (f16)a.w;
  o.h[4] = (f16)b2.x; o.h[5] = (f16)b2.y; o.h[6] = (f16)b2.z; o.h[7] = (f16)b2.w;
  ((float4*)Wp)[tid] = o.v;
}

// ---------- persistent LSTM kernel ----------
// 256 blocks x 256 threads, cooperative. Block b owns h/c elements [b*8, b*8+8)
// (gate rows {j, j+2048, j+4096, j+6144}). Weights live in LDS (128 KiB).
// Cross-block exchange: tagged u64 slots {tag=t+1 | h2-pair}, relaxed agent
// atomics only (no acquire/release in the loop -> no cache invalidations).
extern "C" __global__ void __launch_bounds__(NTHR) lstm_main(
    const float* __restrict__ Wih, const float* __restrict__ bih,
    const float* __restrict__ bhh, const f16* __restrict__ Wp,
    float* __restrict__ outputs, u64t* __restrict__ tagged) {
  extern __shared__ char smem[];
  f16*   w_lds  = (f16*)smem;                        // 65536 halves = 128 KiB
  u32t*  h2_lds = (u32t*)(smem + 131072);            // [c:4][lane:64][4 pairs] = 4 KiB
  float* g_buf  = (float*)(smem + 131072 + 4096);    // 32 f32
  float* xg_s   = g_buf + 32;                        // 32 f32

  const int b   = blockIdx.x;
  const int tid = threadIdx.x;
  const int w   = tid >> 6;
  const int ln  = tid & 63;

  {  // stage this block's weights into LDS once
    const float4* src = (const float4*)(Wp + (size_t)b * 65536);
    float4* dst = (float4*)w_lds;
    for (int i = tid; i < 8192; i += NTHR) dst[i] = src[i];
  }
  {  // compute x_gates for this block's 32 rows (wave w -> rows w*8..w*8+7)
    for (int r = 0; r < 8; ++r) {
      int grow = w * NOP + b * 8 + r;  // gate w, element b*8+r
      const float4* src = (const float4*)(Wih + (size_t)grow * NOP) + ln * 8;
      float s = 0.f;
#pragma unroll
      for (int c = 0; c < 8; ++c) {
        float4 v = src[c];
        s += v.x + v.y + v.z + v.w;
      }
      s = wave_sum63(s);
      if (ln == 63) xg_s[w * 8 + r] = s * (1.0f / NOP) + bih[grow] + bhh[grow];
    }
  }
  float c_state = 0.f;  // live in wave0 lanes 0..7 only
  __syncthreads();

  for (int t = 0; t < NACT; ++t) {
    if (t > 0) {
      // ---- poll exactly the 4 h-pairs this lane consumes (tag == t) ----
      const u64t* base = tagged + (size_t)(t - 1) * 1024 + (ln * 16 + w * 4);
      const u32t want = (u32t)t;
      u64t x0, x1, x2, x3;
      for (;;) {
        x0 = __hip_atomic_load(base + 0, __ATOMIC_RELAXED, __HIP_MEMORY_SCOPE_AGENT);
        x1 = __hip_atomic_load(base + 1, __ATOMIC_RELAXED, __HIP_MEMORY_SCOPE_AGENT);
        x2 = __hip_atomic_load(base + 2, __ATOMIC_RELAXED, __HIP_MEMORY_SCOPE_AGENT);
        x3 = __hip_atomic_load(base + 3, __ATOMIC_RELAXED, __HIP_MEMORY_SCOPE_AGENT);
        bool good = ((u32t)x0 == want) & ((u32t)x1 == want) &
                    ((u32t)x2 == want) & ((u32t)x3 == want);
        if (__all(good)) break;
      }
      // stash pairs into LDS: [c=w][ln][4 pairs] (contiguous b128)
      uint4 hd;
      hd.x = (u32t)(x0 >> 32); hd.y = (u32t)(x1 >> 32);
      hd.z = (u32t)(x2 >> 32); hd.w = (u32t)(x3 >> 32);
      *((uint4*)(h2_lds + ((w * 64 + ln) * 4))) = hd;
      __syncthreads();  // (A)

      // ---- matvec: wave w owns local rows w*8..w*8+7; lane ln k-slice ln*32.. ----
      float4 hreg[4];
#pragma unroll
      for (int c = 0; c < 4; ++c)
        hreg[c] = *((const float4*)(h2_lds + ((c * 64 + ln) * 4)));

#pragma unroll
      for (int r = 0; r < 8; ++r) {
        float acc = 0.f;
#pragma unroll
        for (int c = 0; c < 4; ++c) {
          float4 wv = *((const float4*)(w_lds + (((((w * 8 + r) * 4) + c) * 64 + ln) * 8)));
          acc = dot8(wv, hreg[c], acc);
        }
        acc = wave_sum63(acc);
        if (ln == 63) g_buf[w * 8 + r] = acc + xg_s[w * 8 + r];
      }
    } else {
      if (tid < 32) g_buf[tid] = xg_s[tid];  // h(0)=0 -> g = x_gates
    }
    __syncthreads();  // (B)

    // ---- gate activations + state update + publish (wave 0, lanes 0..7) ----
    if (w == 0 && ln < 8) {
      float gi = g_buf[ln],      gf = g_buf[8 + ln];
      float gc = g_buf[16 + ln], go = g_buf[24 + ln];
      float i_ = sigmoid_f(gi);
      float f_ = sigmoid_f(gf);
      float g_ = tanh_f(gc);
      float o_ = sigmoid_f(go);
      c_state = f_ * c_state + i_ * g_;
      float h = o_ * tanh_f(c_state);
      outputs[(size_t)t * NOP + b * 8 + ln] = h;  // plain store; phase2 reads after kernel end
      // pack pairs: lane i<4 takes h from lanes 2i, 2i+1 (all within active lanes 0..7)
      float he = __shfl(h, 2 * ln);
      float ho = __shfl(h, 2 * ln + 1);
      if (ln < 4 && t < NACT - 1) {
        union { f16 q[2]; u32t u; } pk;
        pk.q[0] = (f16)he; pk.q[1] = (f16)ho;
        u64t val = ((u64t)pk.u << 32) | (u64t)(u32t)(t + 1);
        __hip_atomic_store(&tagged[(size_t)t * 1024 + 4 * b + ln], val,
                           __ATOMIC_RELAXED, __HIP_MEMORY_SCOPE_AGENT);
      }
    }
    // no trailing sync needed: next-step writes to h2_lds/g_buf are gated by (A)
  }
}

// ---------- phase 2: entropy + reinforce ----------
extern "C" __global__ __launch_bounds__(256) void phase2(
    const float* __restrict__ outputs, const float* __restrict__ rewards,
    const int* __restrict__ action, float* __restrict__ accum) {
  __shared__ float sm[4], s1s[4], s2s[4];
  __shared__ float bc[2];
  const int t = blockIdx.x, tid = threadIdx.x, w = tid >> 6, ln = tid & 63;
  const float* row = outputs + (size_t)t * NOP;
  const float4* r4 = (const float4*)row;
  float4 a = r4[tid], b4 = r4[tid + 256];

  float m = fmaxf(fmaxf(fmaxf(a.x, a.y), fmaxf(a.z, a.w)),
                  fmaxf(fmaxf(b4.x, b4.y), fmaxf(b4.z, b4.w)));
#pragma unroll
  for (int off = 32; off >= 1; off >>= 1) m = fmaxf(m, __shfl_xor(m, off));
  if (ln == 0) sm[w] = m;
  __syncthreads();
  if (tid == 0) bc[0] = fmaxf(fmaxf(sm[0], sm[1]), fmaxf(sm[2], sm[3]));
  __syncthreads();
  const float M = bc[0];

  float s1 = 0.f, s2 = 0.f;
  {
    float xs[8] = {a.x, a.y, a.z, a.w, b4.x, b4.y, b4.z, b4.w};
#pragma unroll
    for (int u = 0; u < 8; ++u) {
      float d = xs[u] - M;
      float p = __expf(d);
      s1 += p;
      s2 += d * p;
    }
  }
#pragma unroll
  for (int off = 32; off >= 1; off >>= 1) {
    s1 += __shfl_xor(s1, off);
    s2 += __shfl_xor(s2, off);
  }
  if (ln == 0) { s1s[w] = s1; s2s[w] = s2; }
  __syncthreads();
  if (tid == 0) {
    float S1 = s1s[0] + s1s[1] + s1s[2] + s1s[3];
    float S2 = s2s[0] + s2s[1] + s2s[2] + s2s[3];
    float lse = M + logf(S1);
    atomicAdd(&accum[1], logf(S1) - S2 / S1);  // entropy of this row
    bc[1] = lse;
  }
  __syncthreads();
  if (tid < 32) {  // tid == batch index b
    int ai = action[tid * NACT + t] & (NOP - 1);
    float val = row[ai] - bc[1];
    float rr = rewards[tid] * val;
#pragma unroll
    for (int off = 16; off >= 1; off >>= 1) rr += __shfl_xor(rr, off);
    if (tid == 0) atomicAdd(&accum[0], rr);  // sum of rewards*gathered
  }
}

extern "C" __global__ void finalize(const float* __restrict__ accum,
                                    float* __restrict__ out) {
  // loss = (-sum(rewards*gathered) + NB*entropy_sum)/NB
  out[0] = accum[1] - accum[0] * (1.0f / NB);
}

// ---------- launch ----------
extern "C" void kernel_launch(void* const* d_in, const int* in_sizes, int n_in,
                              void* d_out, int out_size, void* d_ws, size_t ws_size,
                              hipStream_t stream) {
  const float* W_ih    = (const float*)d_in[0];
  const float* W_hh    = (const float*)d_in[1];
  const float* b_ih    = (const float*)d_in[2];
  const float* b_hh    = (const float*)d_in[3];
  const float* rewards = (const float*)d_in[4];
  const int*   action  = (const int*)d_in[5];

  char* ws = (char*)d_ws;
  u64t*  tagged  = (u64t*)ws;                         // [0, 8 MiB): 1024 steps x 1024 slots x 8B
  float* outputs = (float*)(ws + 8u * 1024 * 1024);   // [8, 16 MiB)
  f16*   Wp      = (f16*)(ws + 16u * 1024 * 1024);    // [16, 48 MiB)
  // accum hides in the never-used t=1023 tag slice
  float* accum   = (float*)(ws + (size_t)1023 * 1024 * 8);

  hipMemsetAsync(accum, 0, 256, stream);  // zero the two accumulators

  hipLaunchKernelGGL(prep_pack, dim3(NROWS), dim3(256), 0, stream, W_hh, Wp);

  const unsigned smem = 131072 + 4096 + 256;  // weights + h2 + g_buf/xg_s
  hipFuncSetAttribute((const void*)lstm_main,
                      hipFuncAttributeMaxDynamicSharedMemorySize, (int)smem);
  void* args[] = {(void*)&W_ih, (void*)&b_ih, (void*)&b_hh,
                  (void*)&Wp, (void*)&outputs, (void*)&tagged};
  hipLaunchCooperativeKernel((void*)lstm_main, dim3(NBLK), dim3(NTHR), args,
                             smem, stream);

  hipLaunchKernelGGL(phase2, dim3(NACT), dim3(256), 0, stream,
                     outputs, rewards, action, accum);
  hipLaunchKernelGGL(finalize, dim3(1), dim3(1), 0, stream, accum, (float*)d_out);
}